// Round 9
// baseline (1393.099 us; speedup 1.0000x reference)
//
#include <hip/hip_runtime.h>
#include <cstdint>

#define T_STEPS 128
#define BATCH   1024
#define D_INPUT 96
#define H_DIM   128
#define NWIN    163   // 121 full 7-frame windows + 6 prefix partials + 36 clipped partials

// window table: widx -> (start frame, length)
__device__ __forceinline__ void win_decode(int widx, int& start, int& len) {
    if (widx < 121)      { start = widx;        len = 7; }            // [w, w+6]
    else if (widx < 127) { start = 0;           len = widx - 120; }   // s=0 grow, len 1..6
    else { const int r = widx - 127; const int s = 1 + r / 6;
           len = 1 + r % 6;          start = 7 * s - 1; }             // s>=1 grow partials
}

// (t, s) -> widx, or -1 when the reference window is empty (cur1 == +0)
__device__ __forceinline__ int widx_for(int t, int s) {
    if (t >= 49) return t - 49 + 7 * s;                 // slide regime: full windows
    if (s == 0)  return 121 + min(5, t);                // [0, min(5,t)]
    const int st = 7 * s - 1;
    if (t < st) return -1;
    const int len = min(7, t - st + 1);
    return (len == 7) ? st : (127 + (s - 1) * 6 + (len - 1));
}

// XOR swizzle keeping even/odd float2 pairs adjacent and 8B-aligned
__device__ __forceinline__ int swz_idx(int row, int col) {
    return (row << 7) | (col ^ ((row & 63) << 1));
}

__device__ __forceinline__ float rl_f(float v, int lane) {
    return __uint_as_float((uint32_t)__builtin_amdgcn_readlane((int)__float_as_uint(v), lane));
}

// ---------------------------------------------------------------------------
// kA: CUR1[widx][b][h] = seqFMA_{d}( wsum[d], Win[h][d] ) — bit-identical
// arithmetic (ascending-k frame adds, ascending-d single-acc fmaf).
// Round 9: window sums preloaded into 16 regs/lane and broadcast per (d,q)
// via v_readlane (SGPR operand of the fma) — the only in-loop LDS op is the
// 1 ds_read_b64 of wT per d. 60 KB LDS -> 2 blocks/CU.
// ---------------------------------------------------------------------------
__global__ __launch_bounds__(256) void kA_wincur(const float* __restrict__ x,
                                                 const float* __restrict__ Win,
                                                 float* __restrict__ CUR1) {
    __shared__ float xs[32 * D_INPUT + 32];             // xs[bq*96 + d] (+pad for preload)
    __shared__ float wT[D_INPUT * H_DIM];               // 48 KB, wT[swz_idx(d,h)]
    const int widx = blockIdx.x;
    const int b0   = blockIdx.y * 32;
    int start, len; win_decode(widx, start, len);
    const int tid = threadIdx.x;

    // stage Win transposed (coalesced read, swizzled one-time LDS write)
    for (int e = tid; e < H_DIM * D_INPUT; e += 256) {
        const int h = e / D_INPUT, d = e % D_INPUT;     // Win flat = h*96 + d
        wT[swz_idx(d, h)] = Win[e];
    }
    // window sums (exact ascending-frame adds); coalesced reads & LDS writes
    for (int e = tid; e < 32 * D_INPUT; e += 256) {
        const int bq = e / D_INPUT, d = e % D_INPUT;
        const float* xp = x + ((size_t)start * BATCH + b0 + bq) * D_INPUT + d;
        float s = xp[0];
        for (int k = 1; k < len; ++k)
            s = __fadd_rn(s, xp[(size_t)k * BATCH * D_INPUT]);
        xs[bq * D_INPUT + d] = s;                       // bank = d%32: conflict-free
    }
    __syncthreads();

    const int lane = tid & 63, g = tid >> 6;            // wave g owns b-octet 8g..8g+7
    const int h0 = lane << 1;

    // preload this wave's 768 window sums: wsreg[q + 8*hi], lane = d&63
    float wsreg[16];
#pragma unroll
    for (int r = 0; r < 16; ++r)                        // r = q + 8*hi
        wsreg[r] = xs[(8 * (tid >> 6) + (r & 7)) * D_INPUT + ((r >> 3) << 6) + lane];

    float acc[8][2];
#pragma unroll
    for (int q = 0; q < 8; ++q) { acc[q][0] = 0.f; acc[q][1] = 0.f; }

    // ascending d, one accumulator per (b,h) — bit-exact sgemm order.
    // phase A: d = 0..63 (reg q), phase B: d = 64..95 (reg q+8); lane = d&63.
#pragma unroll 8
    for (int d = 0; d < 64; ++d) {
        const float2 wp = *(const float2*)&wT[swz_idx(d, h0)];   // ds_read_b64
#pragma unroll
        for (int q = 0; q < 8; ++q) {
            const float xv = rl_f(wsreg[q], d);
            acc[q][0] = __fmaf_rn(xv, wp.x, acc[q][0]);
            acc[q][1] = __fmaf_rn(xv, wp.y, acc[q][1]);
        }
    }
#pragma unroll 8
    for (int d = 64; d < D_INPUT; ++d) {
        const float2 wp = *(const float2*)&wT[swz_idx(d, h0)];
#pragma unroll
        for (int q = 0; q < 8; ++q) {
            const float xv = rl_f(wsreg[q + 8], d - 64);
            acc[q][0] = __fmaf_rn(xv, wp.x, acc[q][0]);
            acc[q][1] = __fmaf_rn(xv, wp.y, acc[q][1]);
        }
    }

    float* op = CUR1 + ((size_t)widx * BATCH + b0 + g * 8) * H_DIM + h0;
#pragma unroll
    for (int q = 0; q < 8; ++q) {
        float2 o; o.x = acc[q][0]; o.y = acc[q][1];
        *(float2*)(op + (size_t)q * H_DIM) = o;
    }
}

// ---------------------------------------------------------------------------
// kB: 7 SNN steps, 16 (t,b) pairs per wave, 8 waves/block. W_h0 repacked in
// LDS as per-(j,lane) float4 {W[i0][2j],W[i1][2j],W[i0][2j+1],W[i1][2j+1]}
// (64 KB, naturally conflict-free b128). Spike {0,1} floats stay in lane
// registers; the j-loop broadcasts them via v_readlane -> SGPR operand of
// v_fma (no ballots, no sf LDS strip — round 8's LDS issue pipe was the
// binding resource at ~59% VALU). Per j: 1 b128 + 32 readlane + 64 fma.
// Bit-exact: same {0,1} values, same ascending-h single-accumulator fmaf
// chain; membranes rn(rn(0.9*m)+c) with select-0 reset. Linear W_out /
// mem_out tail relaxed (per-lane Horner + butterfly). 64 KB LDS -> 2
// blocks/CU. __launch_bounds__(512,2): VGPR cap 256 (spill guard).
// ---------------------------------------------------------------------------
__global__ __launch_bounds__(512, 2) void kB_snn(const float* __restrict__ CUR1,
                                                 const float* __restrict__ Wh0,
                                                 const float* __restrict__ Wout,
                                                 const float* __restrict__ vxp,
                                                 const float* __restrict__ vyp,
                                                 float* __restrict__ out) {
    __shared__ float lwq[64 * 64 * 4];                  // 64 KB, float4 per (j,lane)
    const int tid = threadIdx.x;
    // gathered global read (L1/L2-served, one-time), coalesced LDS write
    for (int f = tid; f < 4096; f += 512) {
        const int j = f >> 6, l = f & 63;
        float4 v;
        v.x = Wh0[(2 * l    ) * H_DIM + 2 * j    ];
        v.y = Wh0[(2 * l + 1) * H_DIM + 2 * j    ];
        v.z = Wh0[(2 * l    ) * H_DIM + 2 * j + 1];
        v.w = Wh0[(2 * l + 1) * H_DIM + 2 * j + 1];
        *(float4*)&lwq[f << 2] = v;
    }
    __syncthreads();

    const int w = tid >> 6, lane = tid & 63;
    const int t  = blockIdx.y;
    const int i0 = lane << 1;
    const float wex = Wout[i0],     wey = Wout[H_DIM + i0];
    const float wox = Wout[i0 + 1], woy = Wout[H_DIM + i0 + 1];
    const float vx = vxp[0], vy = vyp[0];
    const int b0 = (blockIdx.x << 7) + (w << 4);        // 16 consecutive b per wave

    float m1a[16], m1b[16], m2a[16], m2b[16], poa[16], pob[16];
    float c1a[16], c1b[16];
    bool  s1a[16], s1b[16], s2a[16], s2b[16];
#pragma unroll
    for (int k = 0; k < 16; ++k) {
        m1a[k]=0.f; m1b[k]=0.f; m2a[k]=0.f; m2b[k]=0.f; poa[k]=0.f; pob[k]=0.f;
        s1a[k]=false; s1b[k]=false; s2a[k]=false; s2b[k]=false;
    }

    // load cur1 for s = 0
    {
        const int wi = widx_for(t, 0);
#pragma unroll
        for (int k = 0; k < 16; ++k) {
            c1a[k] = 0.f; c1b[k] = 0.f;
            if (wi >= 0) {
                const float2 v = *(const float2*)
                    &CUR1[((size_t)wi * BATCH + b0 + k) * H_DIM + i0];
                c1a[k] = v.x; c1b[k] = v.y;
            }
        }
    }

#pragma unroll 1
    for (int s = 0; s < 7; ++s) {
        // ---- mem1 update + spike floats in registers (exact) ---------------
        float sev[16], sov[16];
#pragma unroll
        for (int k = 0; k < 16; ++k) {
            m1a[k] = s1a[k] ? 0.f : __fadd_rn(__fmul_rn(0.9f, m1a[k]), c1a[k]);
            m1b[k] = s1b[k] ? 0.f : __fadd_rn(__fmul_rn(0.9f, m1b[k]), c1b[k]);
            s1a[k] = m1a[k] > 0.5f; s1b[k] = m1b[k] > 0.5f;
            sev[k] = s1a[k] ? 1.0f : 0.0f;              // v_cndmask, once per step
            sov[k] = s1b[k] ? 1.0f : 0.0f;
        }

        // ---- prefetch next step's cur1 into the now-dead c1 registers ------
        const int win = (s < 6) ? widx_for(t, s + 1) : -1;
#pragma unroll
        for (int k = 0; k < 16; ++k) {
            c1a[k] = 0.f; c1b[k] = 0.f;
            if (win >= 0) {
                const float2 v = *(const float2*)
                    &CUR1[((size_t)win * BATCH + b0 + k) * H_DIM + i0];
                c1a[k] = v.x; c1b[k] = v.y;
            }
        }

        // ---- dense cur2: ascending h, readlane-broadcast spikes (exact) ----
        float c2a[16], c2b[16];
#pragma unroll
        for (int k = 0; k < 16; ++k) { c2a[k] = 0.f; c2b[k] = 0.f; }
#pragma unroll 4
        for (int j = 0; j < 64; ++j) {
            const float4 wq = *(const float4*)&lwq[((j << 6) | lane) << 2]; // b128
#pragma unroll
            for (int k = 0; k < 16; ++k) {
                const float se = rl_f(sev[k], j);       // spike(h=2j,   pair k)
                const float so = rl_f(sov[k], j);       // spike(h=2j+1, pair k)
                c2a[k] = __fmaf_rn(se, wq.x, c2a[k]);   // h = 2j
                c2b[k] = __fmaf_rn(se, wq.y, c2b[k]);
                c2a[k] = __fmaf_rn(so, wq.z, c2a[k]);   // h = 2j+1
                c2b[k] = __fmaf_rn(so, wq.w, c2b[k]);
            }
        }

        // ---- mem2 + spikes (exact) and linear output tail (relaxed) --------
#pragma unroll
        for (int k = 0; k < 16; ++k) {
            m2a[k] = s2a[k] ? 0.f : __fadd_rn(__fmul_rn(0.9f, m2a[k]), c2a[k]);
            m2b[k] = s2b[k] ? 0.f : __fadd_rn(__fmul_rn(0.9f, m2b[k]), c2b[k]);
            s2a[k] = m2a[k] > 0.5f; s2b[k] = m2b[k] > 0.5f;
            const float p0 = (s2a[k] ? wex : 0.f) + (s2b[k] ? wox : 0.f);
            const float p1 = (s2a[k] ? wey : 0.f) + (s2b[k] ? woy : 0.f);
            poa[k] = __fmaf_rn(0.9f, poa[k], p0);       // mem_out is linear: order-safe
            pob[k] = __fmaf_rn(0.9f, pob[k], p1);
        }
    }

    // ---- reduce per-lane output partials, write -----------------------------
#pragma unroll
    for (int k = 0; k < 16; ++k) {
        float r0 = poa[k], r1 = pob[k];
#pragma unroll
        for (int off = 32; off > 0; off >>= 1) {
            r0 += __shfl_xor(r0, off);
            r1 += __shfl_xor(r1, off);
        }
        if (lane == 0) {
            float2 o;
            o.x = __fmul_rn(r0, vx);
            o.y = __fmul_rn(r1, vy);
            *(float2*)(out + ((size_t)t * BATCH + b0 + k) * 2) = o;
        }
    }
}

// ---------------------------------------------------------------------------
extern "C" void kernel_launch(void* const* d_in, const int* in_sizes, int n_in,
                              void* d_out, int out_size, void* d_ws, size_t ws_size,
                              hipStream_t stream) {
    const float* x    = (const float*)d_in[0];   // (128,1024,96)
    const float* Win  = (const float*)d_in[1];   // (128,96)
    const float* Wh0  = (const float*)d_in[2];   // (128,128)
    const float* Wout = (const float*)d_in[3];   // (2,128)
    const float* vx   = (const float*)d_in[4];   // (1,)
    const float* vy   = (const float*)d_in[5];   // (1,)
    float* out  = (float*)d_out;                 // (128,1024,2)
    float* CUR1 = (float*)d_ws;                  // 163*1024*128*4 = 85.5 MB

    kA_wincur<<<dim3(NWIN, BATCH / 32),    dim3(256), 0, stream>>>(x, Win, CUR1);
    kB_snn   <<<dim3(BATCH / 128, T_STEPS), dim3(512), 0, stream>>>(CUR1, Wh0, Wout, vx, vy, out);
}

// Round 10
// 1184.873 us; speedup vs baseline: 1.1757x; 1.1757x over previous
//
#include <hip/hip_runtime.h>
#include <cstdint>

#define T_STEPS 128
#define BATCH   1024
#define D_INPUT 96
#define H_DIM   128
#define NWIN    163   // 121 full 7-frame windows + 6 prefix partials + 36 clipped partials

// window table: widx -> (start frame, length)
__device__ __forceinline__ void win_decode(int widx, int& start, int& len) {
    if (widx < 121)      { start = widx;        len = 7; }            // [w, w+6]
    else if (widx < 127) { start = 0;           len = widx - 120; }   // s=0 grow, len 1..6
    else { const int r = widx - 127; const int s = 1 + r / 6;
           len = 1 + r % 6;          start = 7 * s - 1; }             // s>=1 grow partials
}

// (t, s) -> widx, or -1 when the reference window is empty (cur1 == +0)
__device__ __forceinline__ int widx_for(int t, int s) {
    if (t >= 49) return t - 49 + 7 * s;                 // slide regime: full windows
    if (s == 0)  return 121 + min(5, t);                // [0, min(5,t)]
    const int st = 7 * s - 1;
    if (t < st) return -1;
    const int len = min(7, t - st + 1);
    return (len == 7) ? st : (127 + (s - 1) * 6 + (len - 1));
}

__device__ __forceinline__ float rl_f(float v, int lane) {
    return __uint_as_float((uint32_t)__builtin_amdgcn_readlane((int)__float_as_uint(v), lane));
}

// ---------------------------------------------------------------------------
// kA: CUR1[widx][b][h] = seqFMA_{d}( wsum[d], Win[h][d] ) — bit-identical
// arithmetic (ascending-k frame adds, ascending-d single-acc fmaf).
// Round 10: lane = batch. Window sums live in 96 VGPRs (per-lane global
// gathers, L3-served); Win[h][d] is wave-UNIFORM -> s_load, fed to v_fma as
// the SGPR operand — zero broadcast cost, zero LDS. 4 h-chains for ILP.
// __launch_bounds__(256,3): 3 waves/SIMD, VGPR cap ~170 (2nd arg acts as
// min workgroups/CU on this toolchain — round 9 post-mortem).
// ---------------------------------------------------------------------------
__global__ __launch_bounds__(256, 3) void kA_wincur(const float* __restrict__ x,
                                                    const float* __restrict__ Win,
                                                    float* __restrict__ CUR1) {
    const int widx = blockIdx.x;
    int start, len; win_decode(widx, start, len);
    const int tid = threadIdx.x;
    const int w = tid >> 6, lane = tid & 63;
    const int b = blockIdx.y * 256 + w * 64 + lane;     // lane = batch

    // window sums into registers, ascending frame order (exact)
    float xs[D_INPUT];
    const float* xp = x + ((size_t)start * BATCH + b) * D_INPUT;
#pragma unroll
    for (int d = 0; d < D_INPUT; d += 4) {
        const float4 v = *(const float4*)(xp + d);      // per-lane gather, row-local
        xs[d] = v.x; xs[d+1] = v.y; xs[d+2] = v.z; xs[d+3] = v.w;
    }
    for (int k = 1; k < len; ++k) {
        const float* xk = xp + (size_t)k * BATCH * D_INPUT;
#pragma unroll
        for (int d = 0; d < D_INPUT; d += 4) {
            const float4 v = *(const float4*)(xk + d);
            xs[d]   = __fadd_rn(xs[d],   v.x);
            xs[d+1] = __fadd_rn(xs[d+1], v.y);
            xs[d+2] = __fadd_rn(xs[d+2], v.z);
            xs[d+3] = __fadd_rn(xs[d+3], v.w);
        }
    }

    float* op = CUR1 + ((size_t)widx * BATCH + b) * H_DIM;
#pragma unroll 1
    for (int h4 = 0; h4 < H_DIM; h4 += 4) {             // 4 independent chains
        const float* w0 = Win + (size_t)h4 * D_INPUT;   // uniform -> s_loads
        float a0 = 0.f, a1 = 0.f, a2 = 0.f, a3 = 0.f;
#pragma unroll
        for (int d = 0; d < D_INPUT; ++d) {             // ascending d, 1 acc (exact)
            const float xv = xs[d];
            a0 = __fmaf_rn(xv, w0[d              ], a0);
            a1 = __fmaf_rn(xv, w0[d +     D_INPUT], a1);
            a2 = __fmaf_rn(xv, w0[d + 2 * D_INPUT], a2);
            a3 = __fmaf_rn(xv, w0[d + 3 * D_INPUT], a3);
        }
        float4 o; o.x = a0; o.y = a1; o.z = a2; o.w = a3;
        *(float4*)(op + h4) = o;                        // 16B scatter (stride 512B)
    }
}

// ---------------------------------------------------------------------------
// kB: 7 SNN steps, 16 (t,b) pairs per wave in TWO groups of 8 (register
// budget), 8 waves/block. W_h0 in LDS as per-(j,lane) float4 — the ONLY
// in-loop LDS op (1 b128/j; round 8 showed LDS return-BW binds at 10/j).
// Spike {0,1} floats stay in lane registers and are broadcast per (j,k) via
// v_readlane -> SGPR operand of v_fma: 6 VALU/(j,k) = 1.5x the fma floor.
// Round 9's version of this spilled: __launch_bounds__ 2nd arg is min
// WORKGROUPS/CU here, so (512,2) capped VGPR at 128. Now (512,1) -> cap 256.
// Bit-exact: same {0,1} values, same ascending-h single-accumulator fmaf
// chain; membranes rn(rn(0.9*m)+c) with select-0 reset. Linear W_out/mem_out
// tail relaxed: s2 history packed 2 bits/step in hist[k], decoded once.
// ---------------------------------------------------------------------------
__global__ __launch_bounds__(512, 1) void kB_snn(const float* __restrict__ CUR1,
                                                 const float* __restrict__ Wh0,
                                                 const float* __restrict__ Wout,
                                                 const float* __restrict__ vxp,
                                                 const float* __restrict__ vyp,
                                                 float* __restrict__ out) {
    __shared__ float lwq[64 * 64 * 4];                  // 64 KB, float4 per (j,lane)
    const int tid = threadIdx.x;
    for (int f = tid; f < 4096; f += 512) {
        const int j = f >> 6, l = f & 63;
        float4 v;
        v.x = Wh0[(2 * l    ) * H_DIM + 2 * j    ];     // W[i0][2j]
        v.y = Wh0[(2 * l + 1) * H_DIM + 2 * j    ];     // W[i1][2j]
        v.z = Wh0[(2 * l    ) * H_DIM + 2 * j + 1];     // W[i0][2j+1]
        v.w = Wh0[(2 * l + 1) * H_DIM + 2 * j + 1];     // W[i1][2j+1]
        *(float4*)&lwq[f << 2] = v;
    }
    __syncthreads();

    const int w = tid >> 6, lane = tid & 63;
    const int t  = blockIdx.y;
    const int i0 = lane << 1;
    const float wex = Wout[i0],     wey = Wout[H_DIM + i0];
    const float wox = Wout[i0 + 1], woy = Wout[H_DIM + i0 + 1];
    const float vx = vxp[0], vy = vyp[0];
    const int b0 = (blockIdx.x << 7) + (w << 4);        // 16 consecutive b per wave

    float m1a[16], m1b[16], m2a[16], m2b[16], c1a[16], c1b[16];
    uint32_t hist[16];
    bool s1a[16], s1b[16], s2a[16], s2b[16];
#pragma unroll
    for (int k = 0; k < 16; ++k) {
        m1a[k]=0.f; m1b[k]=0.f; m2a[k]=0.f; m2b[k]=0.f; hist[k]=0u;
        s1a[k]=false; s1b[k]=false; s2a[k]=false; s2b[k]=false;
    }

    // load cur1 for s = 0
    {
        const int wi = widx_for(t, 0);
#pragma unroll
        for (int k = 0; k < 16; ++k) {
            c1a[k] = 0.f; c1b[k] = 0.f;
            if (wi >= 0) {
                const float2 v = *(const float2*)
                    &CUR1[((size_t)wi * BATCH + b0 + k) * H_DIM + i0];
                c1a[k] = v.x; c1b[k] = v.y;
            }
        }
    }

#pragma unroll 1
    for (int s = 0; s < 7; ++s) {
        // ---- mem1 update + spike floats in registers (exact) ---------------
        float sev[16], sov[16];
#pragma unroll
        for (int k = 0; k < 16; ++k) {
            m1a[k] = s1a[k] ? 0.f : __fadd_rn(__fmul_rn(0.9f, m1a[k]), c1a[k]);
            m1b[k] = s1b[k] ? 0.f : __fadd_rn(__fmul_rn(0.9f, m1b[k]), c1b[k]);
            s1a[k] = m1a[k] > 0.5f; s1b[k] = m1b[k] > 0.5f;
            sev[k] = s1a[k] ? 1.0f : 0.0f;              // v_cndmask, once per step
            sov[k] = s1b[k] ? 1.0f : 0.0f;
        }

        // ---- prefetch next step's cur1 into the now-dead c1 registers ------
        const int win = (s < 6) ? widx_for(t, s + 1) : -1;
#pragma unroll
        for (int k = 0; k < 16; ++k) {
            c1a[k] = 0.f; c1b[k] = 0.f;
            if (win >= 0) {
                const float2 v = *(const float2*)
                    &CUR1[((size_t)win * BATCH + b0 + k) * H_DIM + i0];
                c1a[k] = v.x; c1b[k] = v.y;
            }
        }

        // ---- dense cur2 in two 8-pair groups (register budget) -------------
#pragma unroll
        for (int g = 0; g < 2; ++g) {
            float c2a[8], c2b[8];
#pragma unroll
            for (int kk = 0; kk < 8; ++kk) { c2a[kk] = 0.f; c2b[kk] = 0.f; }
#pragma unroll 8
            for (int j = 0; j < 64; ++j) {
                const float4 wq = *(const float4*)&lwq[((j << 6) | lane) << 2];
#pragma unroll
                for (int kk = 0; kk < 8; ++kk) {
                    const float se = rl_f(sev[g * 8 + kk], j);   // spike(h=2j)
                    const float so = rl_f(sov[g * 8 + kk], j);   // spike(h=2j+1)
                    c2a[kk] = __fmaf_rn(se, wq.x, c2a[kk]);      // ascending h (exact)
                    c2b[kk] = __fmaf_rn(se, wq.y, c2b[kk]);
                    c2a[kk] = __fmaf_rn(so, wq.z, c2a[kk]);
                    c2b[kk] = __fmaf_rn(so, wq.w, c2b[kk]);
                }
            }
            // ---- mem2 + spikes (exact), pack s2 history (relaxed tail) -----
#pragma unroll
            for (int kk = 0; kk < 8; ++kk) {
                const int k = g * 8 + kk;
                m2a[k] = s2a[k] ? 0.f : __fadd_rn(__fmul_rn(0.9f, m2a[k]), c2a[kk]);
                m2b[k] = s2b[k] ? 0.f : __fadd_rn(__fmul_rn(0.9f, m2b[k]), c2b[kk]);
                s2a[k] = m2a[k] > 0.5f; s2b[k] = m2b[k] > 0.5f;
                hist[k] = (hist[k] << 2) | (s2a[k] ? 1u : 0u) | (s2b[k] ? 2u : 0u);
            }
        }
    }

    // ---- epilogue: decode hist -> Horner g, output dot, butterfly, write ----
#pragma unroll
    for (int k = 0; k < 16; ++k) {
        float ga = 0.f, gb = 0.f;
#pragma unroll
        for (int s = 0; s < 7; ++s) {                   // step s at bits 2*(6-s)
            const uint32_t bits = hist[k] >> (2 * (6 - s));
            ga = __fmaf_rn(0.9f, ga, (bits & 1u) ? 1.f : 0.f);
            gb = __fmaf_rn(0.9f, gb, (bits & 2u) ? 1.f : 0.f);
        }
        float r0 = __fmaf_rn(wex, ga, __fmul_rn(wox, gb));
        float r1 = __fmaf_rn(wey, ga, __fmul_rn(woy, gb));
#pragma unroll
        for (int off = 32; off > 0; off >>= 1) {
            r0 += __shfl_xor(r0, off);
            r1 += __shfl_xor(r1, off);
        }
        if (lane == 0) {
            float2 o;
            o.x = __fmul_rn(r0, vx);
            o.y = __fmul_rn(r1, vy);
            *(float2*)(out + ((size_t)t * BATCH + b0 + k) * 2) = o;
        }
    }
}

// ---------------------------------------------------------------------------
extern "C" void kernel_launch(void* const* d_in, const int* in_sizes, int n_in,
                              void* d_out, int out_size, void* d_ws, size_t ws_size,
                              hipStream_t stream) {
    const float* x    = (const float*)d_in[0];   // (128,1024,96)
    const float* Win  = (const float*)d_in[1];   // (128,96)
    const float* Wh0  = (const float*)d_in[2];   // (128,128)
    const float* Wout = (const float*)d_in[3];   // (2,128)
    const float* vx   = (const float*)d_in[4];   // (1,)
    const float* vy   = (const float*)d_in[5];   // (1,)
    float* out  = (float*)d_out;                 // (128,1024,2)
    float* CUR1 = (float*)d_ws;                  // 163*1024*128*4 = 85.5 MB

    kA_wincur<<<dim3(NWIN, BATCH / 256),    dim3(256), 0, stream>>>(x, Win, CUR1);
    kB_snn   <<<dim3(BATCH / 128, T_STEPS), dim3(512), 0, stream>>>(CUR1, Wh0, Wout, vx, vy, out);
}